// Round 4
// baseline (4197.884 us; speedup 1.0000x reference)
//
#include <hip/hip_runtime.h>
#include <hip/hip_bf16.h>

#define G_ 4
#define E_ 16
#define C_ 2048
#define H_ 512
#define F_ 2048
#define SW1_LD 520   // 512 + 8 pad: ds_read_b128 column reads <=2-way conflict (free, m136)

typedef __attribute__((ext_vector_type(8))) short bf16x8;
typedef __attribute__((ext_vector_type(4))) float f32x4;

__device__ __forceinline__ ushort f2bf(float f){
  uint u = __float_as_uint(f);
  return (ushort)((u + 0x7FFFu + ((u >> 16) & 1u)) >> 16);  // RNE
}

__device__ __forceinline__ bf16x8 pack8(f32x4 a, f32x4 b){
  union { bf16x8 v; uint u[4]; } p;
  p.u[0] = (uint)f2bf(a[0]) | ((uint)f2bf(a[1]) << 16);
  p.u[1] = (uint)f2bf(a[2]) | ((uint)f2bf(a[3]) << 16);
  p.u[2] = (uint)f2bf(b[0]) | ((uint)f2bf(b[1]) << 16);
  p.u[3] = (uint)f2bf(b[2]) | ((uint)f2bf(b[3]) << 16);
  return p.v;
}

__device__ __forceinline__ f32x4 gelu4(f32x4 v){
  f32x4 r;
  #pragma unroll
  for (int i = 0; i < 4; ++i){
    float t = v[i];
    r[i] = 0.5f * t * (1.0f + erff(t * 0.7071067811865475f));  // exact GELU
  }
  return r;
}

// transpose + fp32->bf16 convert: src [E][R][C] fp32 -> dst [E][C][R] bf16
__global__ void transpose_cvt(const float* __restrict__ src, ushort* __restrict__ dst,
                              int R, int C){
  __shared__ float tile[64][65];
  int c0 = blockIdx.x * 64, r0 = blockIdx.y * 64, e = blockIdx.z;
  int tx = threadIdx.x & 63, ty = threadIdx.x >> 6;   // 256 threads
  const float* s = src + (size_t)e * R * C;
  #pragma unroll
  for (int it = 0; it < 16; ++it){
    int row = ty + it * 4;
    tile[row][tx] = s[(size_t)(r0 + row) * C + (c0 + tx)];
  }
  __syncthreads();
  ushort* d = dst + (size_t)e * C * R;
  #pragma unroll
  for (int it = 0; it < 16; ++it){
    int row = ty + it * 4;
    d[(size_t)(c0 + row) * R + (r0 + tx)] = f2bf(tile[tx][row]);
  }
}

// Fused FFN, handoff-free (validated math from R2; only the store dtype changed).
// Block = (expert, 128 rows). 8 waves; wave owns 16 token rows end-to-end.
// GEMM1 swapped: mfma(W1frag, Xfrag) -> D1[f, n], lane holds its own token's h1 values.
// GEMM2 A-frag formed in-register; common k-fill mu(lg,j) = (j>>2)*16 + lg*4 + (j&3)
// used identically for A and B (same-mu cancellation).
__global__ __launch_bounds__(512, 2) void ffn_fused2(
    const float* __restrict__ x,      // [G][E][C][H] fp32
    const float* __restrict__ b1,     // [E][F] fp32
    const float* __restrict__ b2,     // [E][H] fp32
    const ushort* __restrict__ w1t,   // [E][F][H] bf16
    const ushort* __restrict__ w2t,   // [E][H][F] bf16
    float* __restrict__ out){         // [G][E][C][H] fp32  <-- THE FIX
  __shared__ ushort sW1[32 * SW1_LD];
  const int tid  = threadIdx.x;
  const int lane = tid & 63;
  const int wv   = tid >> 6;
  const int l15  = lane & 15;
  const int lg   = lane >> 4;
  const int bid  = blockIdx.x;
  const int e    = bid >> 6;
  const int mb   = bid & 63;
  const int n0   = mb * 128;
  const int g    = n0 >> 11;              // 128 | 2048: never crosses g
  const int c0   = n0 & (C_ - 1);

  // X fragments: lane holds its row (wv*16 + l15), k = kk*32 + lg*8 + j
  const float* xrow = x + ((size_t)(g * E_ + e) * C_ + (c0 + wv * 16 + l15)) * H_;
  bf16x8 xf[16];
  #pragma unroll
  for (int kk = 0; kk < 16; ++kk){
    f32x4 fa = *(const f32x4*)(xrow + kk * 32 + lg * 8);
    f32x4 fb = *(const f32x4*)(xrow + kk * 32 + lg * 8 + 4);
    xf[kk] = pack8(fa, fb);
  }

  f32x4 acc2[32];                         // 128 VGPR
  #pragma unroll
  for (int cf2 = 0; cf2 < 32; ++cf2) acc2[cf2] = (f32x4){0.f, 0.f, 0.f, 0.f};

  const ushort* w2p = w2t + (size_t)e * H_ * F_ + lg * 4;
  const float*  b1p = b1 + (size_t)e * F_ + lg * 4;

  for (int ch = 0; ch < 64; ++ch){
    const int f0 = ch * 32;
    // stage W1 chunk [32 f][512 h] bf16 -> LDS
    {
      const ushort* src = w1t + (size_t)(e * F_ + f0) * H_;
      #pragma unroll
      for (int i = 0; i < 4; ++i){
        int idx  = tid + i * 512;
        int row  = idx >> 6;
        int ecol = (idx & 63) * 8;
        *(uint4*)(&sW1[row * SW1_LD + ecol]) = *(const uint4*)(src + row * H_ + ecol);
      }
    }
    __syncthreads();  // sW1 ready

    // GEMM1 (swapped): lane (l15,lg) gets h1[f0 + cf*16 + lg*4 + i][token wv*16 + l15]
    f32x4 acc1[2];
    acc1[0] = (f32x4){0.f,0.f,0.f,0.f};
    acc1[1] = (f32x4){0.f,0.f,0.f,0.f};
    #pragma unroll
    for (int cf = 0; cf < 2; ++cf){
      const int rbase = (cf * 16 + l15) * SW1_LD;
      #pragma unroll
      for (int kk = 0; kk < 16; ++kk){
        bf16x8 afr = *(const bf16x8*)(&sW1[rbase + kk * 32 + lg * 8]);
        acc1[cf] = __builtin_amdgcn_mfma_f32_16x16x32_bf16(afr, xf[kk], acc1[cf], 0, 0, 0);
      }
    }
    __syncthreads();  // sW1 fully consumed; next chunk may overwrite

    // bias + exact GELU; lane's values: f = f0 + mu(lg,j), token = wv*16 + l15
    f32x4 b1a = *(const f32x4*)(b1p + f0);
    f32x4 b1b = *(const f32x4*)(b1p + f0 + 16);
    bf16x8 pa = pack8(gelu4(acc1[0] + b1a), gelu4(acc1[1] + b1b));

    // GEMM2: acc2[cf2] += a . W2; B elem j = w2t[hcol][f0 + mu(lg,j)]
    #pragma unroll
    for (int cf2 = 0; cf2 < 32; ++cf2){
      const ushort* wrow = w2p + (size_t)(cf2 * 16 + l15) * F_ + f0;
      union { bf16x8 v; uint2 u[2]; } bfr;
      bfr.u[0] = *(const uint2*)(wrow);        // f0 + lg*4 + {0..3}
      bfr.u[1] = *(const uint2*)(wrow + 16);   // f0 + 16 + lg*4 + {0..3}
      acc2[cf2] = __builtin_amdgcn_mfma_f32_16x16x32_bf16(pa, bfr.v, acc2[cf2], 0, 0, 0);
    }
  }

  // epilogue: D2[lg*4+i][l15] -> row = c0 + wv*16 + lg*4 + i, col = cf2*16 + l15 (fp32 stores)
  const size_t obase = (size_t)(g * E_ + e) * C_ + (c0 + wv * 16 + lg * 4);
  #pragma unroll
  for (int cf2 = 0; cf2 < 32; ++cf2){
    const int col  = cf2 * 16 + l15;
    const float bb = b2[e * H_ + col];
    #pragma unroll
    for (int i = 0; i < 4; ++i)
      out[(obase + i) * H_ + col] = acc2[cf2][i] + bb;
  }
}

extern "C" void kernel_launch(void* const* d_in, const int* in_sizes, int n_in,
                              void* d_out, int out_size, void* d_ws, size_t ws_size,
                              hipStream_t stream){
  // Size-based dispatch (no-op under documented dict order; w1/w2 keep relative order)
  const float *x = nullptr, *b1 = nullptr, *b2 = nullptr;
  const float* w12[2] = {nullptr, nullptr}; int nw = 0;
  for (int i = 0; i < n_in; ++i){
    long s = (long)in_sizes[i];
    if      (s == (long)G_ * E_ * C_ * H_) x = (const float*)d_in[i];
    else if (s == (long)E_ * H_ * F_) { if (nw < 2) w12[nw++] = (const float*)d_in[i]; }
    else if (s == (long)E_ * F_) b1 = (const float*)d_in[i];
    else if (s == (long)E_ * H_) b2 = (const float*)d_in[i];
  }
  const float* w1 = w12[0];
  const float* w2 = w12[1];
  if (!x || !w1 || !w2 || !b1 || !b2){
    x  = (const float*)d_in[0];
    w1 = (const float*)d_in[1];
    b1 = (const float*)d_in[2];
    w2 = (const float*)d_in[3];
    b2 = (const float*)d_in[4];
  }

  ushort* w1t = (ushort*)d_ws;                       // [E][F][H] bf16
  ushort* w2t = w1t + (size_t)E_ * F_ * H_;          // [E][H][F] bf16

  transpose_cvt<<<dim3(F_ / 64, H_ / 64, E_), dim3(256), 0, stream>>>(w1, w1t, H_, F_);
  transpose_cvt<<<dim3(H_ / 64, F_ / 64, E_), dim3(256), 0, stream>>>(w2, w2t, F_, H_);

  ffn_fused2<<<dim3(E_ * 64), dim3(512), 0, stream>>>(x, b1, b2, w1t, w2t, (float*)d_out);
}

// Round 5
// 1407.085 us; speedup vs baseline: 2.9834x; 2.9834x over previous
//
#include <hip/hip_runtime.h>
#include <hip/hip_bf16.h>
#include <stdint.h>

#define G_ 4
#define E_ 16
#define C_ 2048
#define H_ 512
#define F_ 2048

typedef __attribute__((ext_vector_type(8))) short bf16x8;
typedef __attribute__((ext_vector_type(4))) float f32x4;
typedef uint32_t u32_glb __attribute__((address_space(1)));
typedef uint32_t u32_lds __attribute__((address_space(3)));

__device__ __forceinline__ ushort f2bf(float f){
  uint u = __float_as_uint(f);
  return (ushort)((u + 0x7FFFu + ((u >> 16) & 1u)) >> 16);  // RNE
}

__device__ __forceinline__ bf16x8 pack8(f32x4 a, f32x4 b){
  union { bf16x8 v; uint u[4]; } p;
  p.u[0] = (uint)f2bf(a[0]) | ((uint)f2bf(a[1]) << 16);
  p.u[1] = (uint)f2bf(a[2]) | ((uint)f2bf(a[3]) << 16);
  p.u[2] = (uint)f2bf(b[0]) | ((uint)f2bf(b[1]) << 16);
  p.u[3] = (uint)f2bf(b[2]) | ((uint)f2bf(b[3]) << 16);
  return p.v;
}

__device__ __forceinline__ f32x4 gelu4(f32x4 v){
  f32x4 r;
  #pragma unroll
  for (int i = 0; i < 4; ++i){
    float t = v[i];
    r[i] = 0.5f * t * (1.0f + erff(t * 0.7071067811865475f));  // exact GELU
  }
  return r;
}

// transpose + fp32->bf16 convert: src [E][R][C] fp32 -> dst [E][C][R] bf16
__global__ void transpose_cvt(const float* __restrict__ src, ushort* __restrict__ dst,
                              int R, int C){
  __shared__ float tile[64][65];
  int c0 = blockIdx.x * 64, r0 = blockIdx.y * 64, e = blockIdx.z;
  int tx = threadIdx.x & 63, ty = threadIdx.x >> 6;   // 256 threads
  const float* s = src + (size_t)e * R * C;
  #pragma unroll
  for (int it = 0; it < 16; ++it){
    int row = ty + it * 4;
    tile[row][tx] = s[(size_t)(r0 + row) * C + (c0 + tx)];
  }
  __syncthreads();
  ushort* d = dst + (size_t)e * C * R;
  #pragma unroll
  for (int it = 0; it < 16; ++it){
    int row = ty + it * 4;
    d[(size_t)(c0 + row) * R + (r0 + tx)] = f2bf(tile[tx][row]);
  }
}

// Fused FFN v3: validated math of R4, restructured memory system.
// - sW1: linear [32][512] double-buffered, staged by global_load_lds(16B) with
//   both-sides XOR swizzle (byte ^ (row&7)<<4), conflict-free b128 reads.
// - sW2: [512][36] (pad) double-buffered, reg-staged; conflict-free b64 reads.
// - One barrier per chunk; chunk t+1 staged while computing chunk t.
__global__ __launch_bounds__(512, 2) void ffn_fused3(
    const float* __restrict__ x,      // [G][E][C][H] fp32
    const float* __restrict__ b1,     // [E][F] fp32
    const float* __restrict__ b2,     // [E][H] fp32
    const ushort* __restrict__ w1t,   // [E][F][H] bf16
    const ushort* __restrict__ w2t,   // [E][H][F] bf16
    float* __restrict__ out){         // [G][E][C][H] fp32
  __shared__ ushort sW1[2][32 * 512];   // 2 x 32 KB, linear (swizzled content)
  __shared__ ushort sW2[2][512 * 36];   // 2 x 36 KB, padded rows
  const int tid  = threadIdx.x;
  const int lane = tid & 63;
  const int wv   = tid >> 6;
  const int l15  = lane & 15;
  const int lg   = lane >> 4;

  // XCD-aware bijective swizzle (1024 blocks = 8 XCDs x 128): experts 2x,2x+1 per XCD
  const int bid  = (blockIdx.x & 7) * 128 + (blockIdx.x >> 3);
  const int e    = bid >> 6;
  const int mb   = bid & 63;
  const int n0   = mb * 128;
  const int g    = n0 >> 11;
  const int c0   = n0 & (C_ - 1);

  // X fragments in registers: lane holds row (wv*16 + l15), k = kk*32 + lg*8 + j
  const float* xrow = x + ((size_t)(g * E_ + e) * C_ + (c0 + wv * 16 + l15)) * H_;
  bf16x8 xf[16];
  #pragma unroll
  for (int kk = 0; kk < 16; ++kk){
    f32x4 fa = *(const f32x4*)(xrow + kk * 32 + lg * 8);
    f32x4 fb = *(const f32x4*)(xrow + kk * 32 + lg * 8 + 4);
    xf[kk] = pack8(fa, fb);
  }

  f32x4 acc2[32];
  #pragma unroll
  for (int cf2 = 0; cf2 < 32; ++cf2) acc2[cf2] = (f32x4){0.f, 0.f, 0.f, 0.f};

  const ushort* w1e = w1t + (size_t)e * F_ * H_;
  const ushort* w2e = w2t + (size_t)e * H_ * F_;
  const float*  b1p = b1 + (size_t)e * F_ + lg * 4;

  uint4 w2r[4];  // W2 staging regs (in flight across compute phase)

  // ---- staging helpers ----
  // W1: DMA rows {wv, wv+8, wv+16, wv+24}; dest linear, source pre-swizzled.
  #define STAGE_W1(F0, NB)                                                        \
    { _Pragma("unroll")                                                           \
      for (int it = 0; it < 4; ++it){                                             \
        int row = wv + it * 8;                                                    \
        const ushort* gsrc = w1e + (size_t)((F0) + row) * H_                      \
                           + (((lane * 16) ^ ((row & 7) << 4)) >> 1);             \
        __builtin_amdgcn_global_load_lds((const u32_glb*)(uintptr_t)gsrc,         \
            (u32_lds*)(uintptr_t)(&sW1[(NB)][row * 512]), 16, 0, 0);              \
      } }
  #define STAGE_W2_ISSUE(F0)                                                     \
    { _Pragma("unroll")                                                           \
      for (int i = 0; i < 4; ++i){                                                \
        int seg = i * 512 + tid;                                                  \
        w2r[i] = *(const uint4*)(w2e + (size_t)(seg >> 2) * F_ + (F0) + (seg & 3) * 8); \
      } }
  #define STAGE_W2_WRITE(NB)                                                     \
    { _Pragma("unroll")                                                           \
      for (int i = 0; i < 4; ++i){                                                \
        int seg = i * 512 + tid;                                                  \
        *(uint4*)(&sW2[(NB)][(seg >> 2) * 36 + (seg & 3) * 8]) = w2r[i];          \
      } }

  // ---- prologue: stage chunk 0 ----
  STAGE_W2_ISSUE(0)
  STAGE_W1(0, 0)
  STAGE_W2_WRITE(0)                      // compiler waits the 4 loads
  asm volatile("s_waitcnt vmcnt(0)" ::: "memory");   // drain W1 DMA
  __syncthreads();

  for (int ch = 0; ch < 64; ++ch){
    const int f0  = ch * 32;
    const int cur = ch & 1, nxt = cur ^ 1;
    if (ch < 63){                        // issue next chunk's loads early (T14)
      STAGE_W2_ISSUE(f0 + 32)
      STAGE_W1(f0 + 32, nxt)
    }

    // GEMM1 (swapped): lane gets h1[f0 + cf*16 + lg*4 + i][token wv*16 + l15]
    f32x4 acc1[2];
    acc1[0] = (f32x4){0.f,0.f,0.f,0.f};
    acc1[1] = (f32x4){0.f,0.f,0.f,0.f};
    #pragma unroll
    for (int cf = 0; cf < 2; ++cf){
      const int r  = cf * 16 + l15;
      const int sw = (r & 7) << 4;
      #pragma unroll
      for (int kk = 0; kk < 16; ++kk){
        bf16x8 afr = *(const bf16x8*)(&sW1[cur][r * 512 + (((kk * 64 + lg * 16) ^ sw) >> 1)]);
        acc1[cf] = __builtin_amdgcn_mfma_f32_16x16x32_bf16(afr, xf[kk], acc1[cf], 0, 0, 0);
      }
    }

    // bias + exact GELU; lane's values: f = f0 + mu(lg,j), token = wv*16 + l15
    f32x4 b1a = *(const f32x4*)(b1p + f0);
    f32x4 b1b = *(const f32x4*)(b1p + f0 + 16);
    bf16x8 pa = pack8(gelu4(acc1[0] + b1a), gelu4(acc1[1] + b1b));

    // GEMM2: B elem j = w2t[h = cf2*16+l15][f0 + mu(lg,j)] from padded sW2
    #pragma unroll
    for (int cf2 = 0; cf2 < 32; ++cf2){
      const ushort* wr = &sW2[cur][(cf2 * 16 + l15) * 36 + lg * 4];
      union { bf16x8 v; uint2 u[2]; } bfr;
      bfr.u[0] = *(const uint2*)(wr);        // f0 + lg*4 + {0..3}
      bfr.u[1] = *(const uint2*)(wr + 16);   // f0 + 16 + lg*4 + {0..3}
      acc2[cf2] = __builtin_amdgcn_mfma_f32_16x16x32_bf16(pa, bfr.v, acc2[cf2], 0, 0, 0);
    }

    if (ch < 63) STAGE_W2_WRITE(nxt)
    asm volatile("s_waitcnt vmcnt(0)" ::: "memory");  // W1 DMA (+W2 loads) landed
    __syncthreads();                      // one barrier per chunk
  }

  // epilogue: D2[lg*4+i][l15] -> row = c0 + wv*16 + lg*4 + i, col = cf2*16 + l15
  const size_t obase = (size_t)(g * E_ + e) * C_ + (c0 + wv * 16 + lg * 4);
  #pragma unroll
  for (int cf2 = 0; cf2 < 32; ++cf2){
    const int col  = cf2 * 16 + l15;
    const float bb = b2[e * H_ + col];
    #pragma unroll
    for (int i = 0; i < 4; ++i)
      out[(obase + i) * H_ + col] = acc2[cf2][i] + bb;
  }
}

extern "C" void kernel_launch(void* const* d_in, const int* in_sizes, int n_in,
                              void* d_out, int out_size, void* d_ws, size_t ws_size,
                              hipStream_t stream){
  const float *x = nullptr, *b1 = nullptr, *b2 = nullptr;
  const float* w12[2] = {nullptr, nullptr}; int nw = 0;
  for (int i = 0; i < n_in; ++i){
    long s = (long)in_sizes[i];
    if      (s == (long)G_ * E_ * C_ * H_) x = (const float*)d_in[i];
    else if (s == (long)E_ * H_ * F_) { if (nw < 2) w12[nw++] = (const float*)d_in[i]; }
    else if (s == (long)E_ * F_) b1 = (const float*)d_in[i];
    else if (s == (long)E_ * H_) b2 = (const float*)d_in[i];
  }
  const float* w1 = w12[0];
  const float* w2 = w12[1];
  if (!x || !w1 || !w2 || !b1 || !b2){
    x  = (const float*)d_in[0];
    w1 = (const float*)d_in[1];
    b1 = (const float*)d_in[2];
    w2 = (const float*)d_in[3];
    b2 = (const float*)d_in[4];
  }

  ushort* w1t = (ushort*)d_ws;                       // [E][F][H] bf16
  ushort* w2t = w1t + (size_t)E_ * F_ * H_;          // [E][H][F] bf16

  transpose_cvt<<<dim3(F_ / 64, H_ / 64, E_), dim3(256), 0, stream>>>(w1, w1t, H_, F_);
  transpose_cvt<<<dim3(H_ / 64, F_ / 64, E_), dim3(256), 0, stream>>>(w2, w2t, F_, H_);

  ffn_fused3<<<dim3(E_ * 64), dim3(512), 0, stream>>>(x, b1, b2, w1t, w2t, (float*)d_out);
}